// Round 1
// 842.055 us; speedup vs baseline: 1.0114x; 1.0114x over previous
//
#include <hip/hip_runtime.h>

#define HALF (1 << 23)   // 2^23 float4-groups per half (dim pairs)
#define BATCH 4

typedef float f32x4 __attribute__((ext_vector_type(4)));

// Single fused kernel: block-local U-matrix computation (threads 0..3, once
// per block — ~60 VALU ops, negligible vs the ~800-cycle/wave memory time),
// then pure-streaming gate application with nontemporal loads/stores
// (zero reuse across the 1.07 GB working set; don't pollute L2/MALL).
// d_ws is intentionally unused.
__global__ __launch_bounds__(256) void apply_gate_fused(
        const float* __restrict__ state_real,
        const float* __restrict__ state_imag,
        const float* __restrict__ thetas,
        float* __restrict__ out) {
    __shared__ float m[32];  // m[c*4 + b], c in {00r,00i,01r,01i,10r,10i,11r,11i}

    if (threadIdx.x < BATCH) {
        const int b = threadIdx.x;
        float phi   = thetas[0 * BATCH + b];
        float theta = thetas[1 * BATCH + b];
        float omega = thetas[2 * BATCH + b];
        float ct = cosf(theta * 0.5f), st = sinf(theta * 0.5f);
        float ap = (phi + omega) * 0.5f;
        float am = (phi - omega) * 0.5f;
        float cp = cosf(ap), sp = sinf(ap);
        float cm = cosf(am), sm = sinf(am);
        // U = RZ(omega) RY(theta) RZ(phi); t_plus = cp - i*sp, t_minus = cm - i*sm
        m[0 * 4 + b] =  ct * cp;   // m00 = ct * t_plus
        m[1 * 4 + b] = -ct * sp;
        m[2 * 4 + b] = -st * cm;   // m01 = -st * conj(t_minus)
        m[3 * 4 + b] = -st * sm;
        m[4 * 4 + b] =  st * cm;   // m10 = st * t_minus
        m[5 * 4 + b] = -st * sm;
        m[6 * 4 + b] =  ct * cp;   // m11 = ct * conj(t_plus)
        m[7 * 4 + b] =  ct * sp;
    }
    __syncthreads();

    // Pull the 32 coefficients into registers via 8 vector LDS reads
    // (same-address across lanes -> broadcast, conflict-free).
    const f32x4* mv = (const f32x4*)m;
    f32x4 c00r = mv[0], c00i = mv[1];
    f32x4 c01r = mv[2], c01i = mv[3];
    f32x4 c10r = mv[4], c10i = mv[5];
    f32x4 c11r = mv[6], c11i = mv[7];

    int i = blockIdx.x * blockDim.x + threadIdx.x;  // float4-group index in [0, HALF)

    const f32x4* sr4 = (const f32x4*)state_real;
    const f32x4* si4 = (const f32x4*)state_imag;
    f32x4* out4 = (f32x4*)out;

    f32x4 v0r = __builtin_nontemporal_load(sr4 + i);
    f32x4 v1r = __builtin_nontemporal_load(sr4 + i + HALF);
    f32x4 v0i = __builtin_nontemporal_load(si4 + i);
    f32x4 v1i = __builtin_nontemporal_load(si4 + i + HALF);

    f32x4 o0r, o0i, o1r, o1i;
#pragma unroll
    for (int k = 0; k < 4; ++k) {
        float ar = v0r[k], ai = v0i[k];   // s0 (lower half)
        float br = v1r[k], bi = v1i[k];   // s1 (upper half)
        // out0 = m00*s0 + m01*s1
        o0r[k] = c00r[k] * ar - c00i[k] * ai + c01r[k] * br - c01i[k] * bi;
        o0i[k] = c00r[k] * ai + c00i[k] * ar + c01r[k] * bi + c01i[k] * br;
        // out1 = m10*s0 + m11*s1
        o1r[k] = c10r[k] * ar - c10i[k] * ai + c11r[k] * br - c11i[k] * bi;
        o1i[k] = c10r[k] * ai + c10i[k] * ar + c11r[k] * bi + c11i[k] * br;
    }

    // Output layout: (2, DIM, B) f32; imag plane starts at 2*HALF in float4 units.
    __builtin_nontemporal_store(o0r, out4 + i);
    __builtin_nontemporal_store(o1r, out4 + i + HALF);
    __builtin_nontemporal_store(o0i, out4 + i + 2 * HALF);
    __builtin_nontemporal_store(o1i, out4 + i + 3 * HALF);
}

extern "C" void kernel_launch(void* const* d_in, const int* in_sizes, int n_in,
                              void* d_out, int out_size, void* d_ws, size_t ws_size,
                              hipStream_t stream) {
    const float* state_real = (const float*)d_in[0];
    const float* state_imag = (const float*)d_in[1];
    const float* thetas     = (const float*)d_in[2];
    float* out = (float*)d_out;
    (void)d_ws; (void)ws_size;

    apply_gate_fused<<<HALF / 256, 256, 0, stream>>>(state_real, state_imag, thetas, out);
}